// Round 4
// baseline (1511.590 us; speedup 1.0000x reference)
//
#include <hip/hip_runtime.h>
#include <math.h>

// ---------------------------------------------------------------------------
// 3-layer GCN on MI355X, fused form.
//   GCNConv: out = relu( A_hat @ (in @ W) + b ),  A_hat = D^-1/2 (A+I) D^-1/2
//   Commute: A_hat @ (in @ W) == (A_hat @ in) @ W   -> aggregate FIRST, then
//   GEMM the aggregated row against LDS-resident W inside the same kernel.
//   No intermediate [N,128] buffer; workspace = CSR only (~8 MB).
// CSR over dst rebuilt on-device every call (no cross-call state; the only
// nondeterminism is eSrc slot order -> fp32 reassociation ~1e-6).
// ---------------------------------------------------------------------------

__global__ __launch_bounds__(256) void k_zero(int* __restrict__ cnt,
                                              int* __restrict__ fillPos, int n) {
  int i = blockIdx.x * blockDim.x + threadIdx.x;
  if (i < n) { cnt[i] = 0; fillPos[i] = 0; }
}

__global__ __launch_bounds__(256) void k_deg(const int* __restrict__ dst,
                                             int* __restrict__ cnt, int E) {
  int i = blockIdx.x * blockDim.x + threadIdx.x;
  int stride = gridDim.x * blockDim.x;
  for (; i < E; i += stride) atomicAdd(&cnt[dst[i]], 1);
}

__global__ __launch_bounds__(256) void k_dinv(const int* __restrict__ cnt,
                                              float* __restrict__ dinv, int n) {
  int i = blockIdx.x * blockDim.x + threadIdx.x;
  if (i < n) dinv[i] = rsqrtf(1.0f + (float)cnt[i]);  // deg includes self-loop
}

// Exclusive scan of cnt[0..n) into exc, chunk=1024 per block (256 thr x 4).
__global__ __launch_bounds__(256) void k_scan1(const int* __restrict__ cnt,
                                               int* __restrict__ exc,
                                               int* __restrict__ bsum, int n) {
  __shared__ int lds[256];
  int t = threadIdx.x;
  int base = blockIdx.x * 1024 + t * 4;
  int v0 = (base + 0 < n) ? cnt[base + 0] : 0;
  int v1 = (base + 1 < n) ? cnt[base + 1] : 0;
  int v2 = (base + 2 < n) ? cnt[base + 2] : 0;
  int v3 = (base + 3 < n) ? cnt[base + 3] : 0;
  int sum = v0 + v1 + v2 + v3;
  lds[t] = sum;
  __syncthreads();
  for (int off = 1; off < 256; off <<= 1) {
    int val = lds[t];
    if (t >= off) val += lds[t - off];
    __syncthreads();
    lds[t] = val;
    __syncthreads();
  }
  int ex = lds[t] - sum;  // exclusive within chunk
  if (base + 0 < n) exc[base + 0] = ex;
  ex += v0;
  if (base + 1 < n) exc[base + 1] = ex;
  ex += v1;
  if (base + 2 < n) exc[base + 2] = ex;
  ex += v2;
  if (base + 3 < n) exc[base + 3] = ex;
  if (t == 255) bsum[blockIdx.x] = lds[255];
}

// Single-block exclusive scan of block sums (nb <= 128).
__global__ __launch_bounds__(128) void k_scan2(int* __restrict__ bsum, int nb) {
  __shared__ int lds[128];
  int t = threadIdx.x;
  int v = (t < nb) ? bsum[t] : 0;
  lds[t] = v;
  __syncthreads();
  for (int off = 1; off < 128; off <<= 1) {
    int val = lds[t];
    if (t >= off) val += lds[t - off];
    __syncthreads();
    lds[t] = val;
    __syncthreads();
  }
  if (t < nb) bsum[t] = lds[t] - v;
}

__global__ __launch_bounds__(256) void k_scan3(int* __restrict__ exc,
                                               const int* __restrict__ bsum, int n) {
  int i = blockIdx.x * blockDim.x + threadIdx.x;
  if (i < n) exc[i] += bsum[i >> 10];
}

__global__ __launch_bounds__(256) void k_fill(const int* __restrict__ src,
                                              const int* __restrict__ dst,
                                              const int* __restrict__ rowStart,
                                              int* __restrict__ fillPos,
                                              int* __restrict__ eSrc, int E) {
  int i = blockIdx.x * blockDim.x + threadIdx.x;
  int stride = gridDim.x * blockDim.x;
  for (; i < E; i += stride) {
    int d = dst[i];
    int p = rowStart[d] + atomicAdd(&fillPos[d], 1);
    eSrc[p] = src[i];
  }
}

// Fused GCN layer: per wave-owned node d,
//   t = dinv[d] * ( sum_{src->d} dinv[src]*in[src] + dinv[d]*in[d] )   [128]
//   out[d] = maybe_relu( t @ W + b )                                   [NFO]
// NFO=128: lane owns out cols {2l,2l+1}; NFO=64: lane owns col l.
// 512 threads = 8 waves share one LDS-resident W (64/32 KB).
template <int NFO, bool RELU>
__global__ __launch_bounds__(512) void k_layer(const float* __restrict__ in,
                                               const float* __restrict__ W,
                                               const float* __restrict__ bias,
                                               const float* __restrict__ dinv,
                                               const int* __restrict__ eSrc,
                                               const int* __restrict__ rowStart,
                                               const int* __restrict__ cnt,
                                               float* __restrict__ out, int n) {
  __shared__ float Wl[128 * NFO];
  for (int t = threadIdx.x; t < 128 * NFO; t += 512) Wl[t] = W[t];
  __syncthreads();
  const int wid = threadIdx.x >> 6, lane = threadIdx.x & 63;
  for (int node = blockIdx.x * 8 + wid; node < n; node += gridDim.x * 8) {
    const int s = rowStart[node], c = cnt[node];
    const int* es = eSrc + s;
    const float dv = dinv[node];
    // self-loop term: dinv[d] * in[d]
    float2 x2 = *(const float2*)&in[(size_t)node * 128 + 2 * lane];
    float ax = dv * x2.x, ay = dv * x2.y;
    int j = 0;
    for (; j + 4 <= c; j += 4) {
      int s0 = es[j], s1 = es[j + 1], s2 = es[j + 2], s3 = es[j + 3];
      float d0 = dinv[s0], d1 = dinv[s1], d2 = dinv[s2], d3 = dinv[s3];
      float2 v0 = *(const float2*)&in[(size_t)s0 * 128 + 2 * lane];
      float2 v1 = *(const float2*)&in[(size_t)s1 * 128 + 2 * lane];
      float2 v2 = *(const float2*)&in[(size_t)s2 * 128 + 2 * lane];
      float2 v3 = *(const float2*)&in[(size_t)s3 * 128 + 2 * lane];
      ax = fmaf(d0, v0.x, ax); ay = fmaf(d0, v0.y, ay);
      ax = fmaf(d1, v1.x, ax); ay = fmaf(d1, v1.y, ay);
      ax = fmaf(d2, v2.x, ax); ay = fmaf(d2, v2.y, ay);
      ax = fmaf(d3, v3.x, ax); ay = fmaf(d3, v3.y, ay);
    }
    for (; j < c; j++) {
      int sj = es[j];
      float dj = dinv[sj];
      float2 v = *(const float2*)&in[(size_t)sj * 128 + 2 * lane];
      ax = fmaf(dj, v.x, ax); ay = fmaf(dj, v.y, ay);
    }
    ax *= dv; ay *= dv;  // t[2*lane], t[2*lane+1]
    // row-GEMM: out_col = sum_k t[k] * W[k][col]
    if constexpr (NFO == 128) {
      float o0 = 0.f, o1 = 0.f;
      #pragma unroll
      for (int kk = 0; kk < 64; kk++) {
        float xa = __shfl(ax, kk);  // t[2kk]
        float xb = __shfl(ay, kk);  // t[2kk+1]
        float2 wA = *(const float2*)&Wl[(2 * kk) * 128 + 2 * lane];
        float2 wB = *(const float2*)&Wl[(2 * kk + 1) * 128 + 2 * lane];
        o0 = fmaf(xa, wA.x, o0); o1 = fmaf(xa, wA.y, o1);
        o0 = fmaf(xb, wB.x, o0); o1 = fmaf(xb, wB.y, o1);
      }
      float2 bb = *(const float2*)&bias[2 * lane];
      float r0 = o0 + bb.x, r1 = o1 + bb.y;
      if (RELU) { r0 = fmaxf(r0, 0.f); r1 = fmaxf(r1, 0.f); }
      *(float2*)&out[(size_t)node * 128 + 2 * lane] = make_float2(r0, r1);
    } else {
      float o0 = 0.f;
      #pragma unroll
      for (int kk = 0; kk < 64; kk++) {
        float xa = __shfl(ax, kk);
        float xb = __shfl(ay, kk);
        o0 = fmaf(xa, Wl[(2 * kk) * NFO + lane], o0);
        o0 = fmaf(xb, Wl[(2 * kk + 1) * NFO + lane], o0);
      }
      float r0 = o0 + bias[lane];
      if (RELU) r0 = fmaxf(r0, 0.f);
      out[(size_t)node * NFO + lane] = r0;
    }
  }
}

extern "C" void kernel_launch(void* const* d_in, const int* in_sizes, int n_in,
                              void* d_out, int out_size, void* d_ws, size_t ws_size,
                              hipStream_t stream) {
  const float* x  = (const float*)d_in[0];
  const int*   ei = (const int*)d_in[1];
  const float* W1 = (const float*)d_in[2];
  const float* b1 = (const float*)d_in[3];
  const float* W2 = (const float*)d_in[4];
  const float* b2 = (const float*)d_in[5];
  const float* W3 = (const float*)d_in[6];
  const float* b3 = (const float*)d_in[7];

  const int N = in_sizes[0] / 128;
  const int E = in_sizes[1] / 2;
  const int* src = ei;
  const int* dst = ei + E;

  // Workspace carve-up (256B aligned). Total ~8.0 MB.
  char* ws = (char*)d_ws;
  size_t off = 0;
  auto alloc = [&](size_t bytes) -> void* {
    void* p = ws + off;
    off = (off + bytes + 255) & ~(size_t)255;
    return p;
  };
  int*   cnt      = (int*)alloc((size_t)N * 4);
  int*   fillPos  = (int*)alloc((size_t)N * 4);
  int*   rowStart = (int*)alloc((size_t)N * 4);
  float* dinv     = (float*)alloc((size_t)N * 4);
  int*   bsum     = (int*)alloc(512);
  int*   eSrc     = (int*)alloc((size_t)E * 4);

  float* y    = (float*)d_out;          // [N,64]
  float* out1 = y + (size_t)N * 64;     // [N,128]
  float* out2 = out1 + (size_t)N * 128; // [N,128]

  // ---- CSR build (fully re-derived from inputs every call) ----
  k_zero<<<(N + 255) / 256, 256, 0, stream>>>(cnt, fillPos, N);
  k_deg<<<2048, 256, 0, stream>>>(dst, cnt, E);
  k_dinv<<<(N + 255) / 256, 256, 0, stream>>>(cnt, dinv, N);
  int nChunks = (N + 1023) / 1024;  // 98 <= 128
  k_scan1<<<nChunks, 256, 0, stream>>>(cnt, rowStart, bsum, N);
  k_scan2<<<1, 128, 0, stream>>>(bsum, nChunks);
  k_scan3<<<(N + 255) / 256, 256, 0, stream>>>(rowStart, bsum, N);
  k_fill<<<2048, 256, 0, stream>>>(src, dst, rowStart, fillPos, eSrc, E);

  // ---- 3 fused GCN layers: aggregate-then-GEMM (A_hat X) W ----
  k_layer<128, true ><<<1024, 512, 0, stream>>>(x,    W1, b1, dinv, eSrc, rowStart, cnt, out1, N);
  k_layer<128, true ><<<1024, 512, 0, stream>>>(out1, W2, b2, dinv, eSrc, rowStart, cnt, out2, N);
  k_layer<64,  false><<<1024, 512, 0, stream>>>(out2, W3, b3, dinv, eSrc, rowStart, cnt, y,    N);
}